// Round 5
// baseline (15512.161 us; speedup 1.0000x reference)
//
#include <hip/hip_runtime.h>
#include <cstdint>
#include <cstring>
#include <vector>
#include <algorithm>

// ---------------------------------------------------------------------------
// GRASPLayer round 5: single-launch GRU with ZERO inter-block communication
// (row-partitioned: block owns 8 rows, h in block-local LDS, W streamed from
// L2). Per-cell accumulation order identical to round-3 PASS -> hfin
// bit-identical. kmeans/gcn/finalk are verbatim round-3 (passing) kernels.
// ---------------------------------------------------------------------------

namespace {
constexpr int Nn = 2048;
constexpr int Tt = 128;
constexpr int Dd = 256;
constexpr int Hh = 256;
constexpr int Kk = 12;
constexpr int MAXIT = 100;
}

struct IdxArgs { int v[Kk]; };

__device__ __forceinline__ float sigm(float x) { return 1.0f / (1.0f + expf(-x)); }

// ---------------------------------------------------------------------------
// Persistent row-local GRU: 256 blocks x 256 threads, 8 rows/block, all 128
// steps in one launch. Thread c computes gate-columns c for all 8 rows.
// h never leaves the block (LDS); only hfin is written to global.
__global__ __launch_bounds__(256, 1) void gru_rows(
    const float* __restrict__ x, const int* __restrict__ len,
    const float* __restrict__ Wih, const float* __restrict__ Whh,
    const float* __restrict__ bih, const float* __restrict__ bhh,
    float* __restrict__ hfin)
{
  __shared__ alignas(16) float xls[8][260];   // x_t rows
  __shared__ alignas(16) float hls[8][260];   // h_{t-1} rows
  const int tid = threadIdx.x;                // output col c
  const int n0 = blockIdx.x * 8;
  const int C = tid;

  const float bi_r = bih[C],          bh_r = bhh[C];
  const float bi_z = bih[Hh + C],     bh_z = bhh[Hh + C];
  const float bi_n = bih[2 * Hh + C], bh_n = bhh[2 * Hh + C];
  int L[8];
  #pragma unroll
  for (int r = 0; r < 8; ++r) L[r] = len[n0 + r];

  const float* __restrict__ wr_base = Wih + (size_t)(0 * Hh + C) * Dd;
  const float* __restrict__ wz_base = Wih + (size_t)(1 * Hh + C) * Dd;
  const float* __restrict__ wn_base = Wih + (size_t)(2 * Hh + C) * Dd;
  const float* __restrict__ ur_base = Whh + (size_t)(0 * Hh + C) * Hh;
  const float* __restrict__ uz_base = Whh + (size_t)(1 * Hh + C) * Hh;
  const float* __restrict__ un_base = Whh + (size_t)(2 * Hh + C) * Hh;

  #pragma unroll
  for (int r = 0; r < 8; ++r) hls[r][tid] = 0.f;

  for (int t = 0; t < Tt; ++t) {
    // stage x_t rows (coalesced float4)
    #pragma unroll
    for (int i = 0; i < 2; ++i) {
      int f = tid + i * 256;                  // 512 float4
      int row = f >> 6, c4 = f & 63;
      *(float4*)&xls[row][c4 * 4] =
          *(const float4*)&x[(size_t)(n0 + row) * (Tt * Dd) + (size_t)t * Dd + c4 * 4];
    }
    __syncthreads();                          // also orders prev-step hls writes

    float aR[8] = {}, aZ[8] = {}, aXN[8] = {}, aHN[8] = {};

    // ---- gx = x_t @ W_ih^T : k ascending 0..255, single fmac chain/cell ----
    for (int k4 = 0; k4 < 64; ++k4) {
      const int k = k4 * 4;
      float4 wr = *(const float4*)&wr_base[k];
      float4 wz = *(const float4*)&wz_base[k];
      float4 wn = *(const float4*)&wn_base[k];
      #pragma unroll
      for (int r = 0; r < 8; ++r) {
        float4 xv = *(const float4*)&xls[r][k];   // same addr all lanes: broadcast
        aR[r]  += xv.x * wr.x; aR[r]  += xv.y * wr.y;
        aR[r]  += xv.z * wr.z; aR[r]  += xv.w * wr.w;
        aZ[r]  += xv.x * wz.x; aZ[r]  += xv.y * wz.y;
        aZ[r]  += xv.z * wz.z; aZ[r]  += xv.w * wz.w;
        aXN[r] += xv.x * wn.x; aXN[r] += xv.y * wn.y;
        aXN[r] += xv.z * wn.z; aXN[r] += xv.w * wn.w;
      }
    }
    // ---- gh = h_{t-1} @ W_hh^T (continues aR/aZ chains; aHN separate) ----
    for (int k4 = 0; k4 < 64; ++k4) {
      const int k = k4 * 4;
      float4 wr = *(const float4*)&ur_base[k];
      float4 wz = *(const float4*)&uz_base[k];
      float4 wn = *(const float4*)&un_base[k];
      #pragma unroll
      for (int r = 0; r < 8; ++r) {
        float4 hv = *(const float4*)&hls[r][k];
        aR[r]  += hv.x * wr.x; aR[r]  += hv.y * wr.y;
        aR[r]  += hv.z * wr.z; aR[r]  += hv.w * wr.w;
        aZ[r]  += hv.x * wz.x; aZ[r]  += hv.y * wz.y;
        aZ[r]  += hv.z * wz.z; aZ[r]  += hv.w * wz.w;
        aHN[r] += hv.x * wn.x; aHN[r] += hv.y * wn.y;
        aHN[r] += hv.z * wn.z; aHN[r] += hv.w * wn.w;
      }
    }
    __syncthreads();                          // readers of hls/xls done

    // ---- gates (order r,z,n; PyTorch layout) + block-local h update ----
    #pragma unroll
    for (int r = 0; r < 8; ++r) {
      if (t < L[r]) {                         // uniform across block threads
        float rg = sigm(aR[r] + bi_r + bh_r);
        float zg = sigm(aZ[r] + bi_z + bh_z);
        float ng = tanhf(aXN[r] + bi_n + rg * (aHN[r] + bh_n));
        float hv = (1.f - zg) * ng + zg * hls[r][C];
        hls[r][C] = hv;                       // own column only
        if (t == L[r] - 1) hfin[(size_t)(n0 + r) * Hh + C] = hv;
      }
    }
    // next loop iteration's __syncthreads orders these writes before reads
  }
}

// ---------------------------------------------------------------------------
__global__ void km_init(const float* __restrict__ dat, float* __restrict__ cent, IdxArgs ia)
{
  int c = threadIdx.x;
  #pragma unroll
  for (int k = 0; k < Kk; ++k)
    cent[k * Hh + c] = dat[(size_t)ia.v[k] * Hh + c];
}

// Assign + per-block partial sums. Deterministic: per-wave LDS partials in
// fixed row order, combined in fixed wave order. No atomics. (round-3 verbatim)
__global__ __launch_bounds__(256) void km_assign(
    const float* __restrict__ dat, const float* __restrict__ cent,
    float* __restrict__ part, int* __restrict__ pcnt)
{
  __shared__ alignas(16) float cs[Kk][Hh];        // centers
  __shared__ alignas(16) float ps[4][Kk][Hh];     // per-wave partial sums
  __shared__ float c2s[Kk];
  __shared__ int pc[4][Kk];
  const int tid = threadIdx.x;
  const int lane = tid & 63;
  const int w = tid >> 6;

  for (int i = tid; i < Kk * Hh; i += 256) ((float*)cs)[i] = cent[i];
  for (int i = tid; i < 4 * Kk * Hh; i += 256) ((float*)ps)[i] = 0.f;
  if (tid < 4 * Kk) ((int*)pc)[tid] = 0;
  __syncthreads();
  if (tid < Kk) {
    float s = 0.f;
    for (int c = 0; c < Hh; ++c) { float v = cs[tid][c]; s += v * v; }
    c2s[tid] = s;
  }
  __syncthreads();

  const int base = blockIdx.x * 64 + w * 16;      // 16 rows per wave
  for (int rr = 0; rr < 16; ++rr) {
    const int n = base + rr;
    float4 v = *(const float4*)&dat[(size_t)n * Hh + lane * 4];
    float best = 3.4e38f; int bi = 0;
    #pragma unroll
    for (int k = 0; k < Kk; ++k) {
      float4 cv = *(const float4*)&cs[k][lane * 4];
      float p = v.x * cv.x + v.y * cv.y + v.z * cv.z + v.w * cv.w;
      #pragma unroll
      for (int m = 1; m < 64; m <<= 1) p += __shfl_xor(p, m, 64);
      float d = c2s[k] - 2.f * p;                 // x^2 constant per row
      if (d < best) { best = d; bi = k; }         // strict <: first-min = argmin
    }
    float4* dst = (float4*)&ps[w][bi][lane * 4];
    float4 cur = *dst;
    cur.x += v.x; cur.y += v.y; cur.z += v.z; cur.w += v.w;
    *dst = cur;
    if (lane == 0) pc[w][bi] += 1;
  }
  __syncthreads();
  const float* p0 = &ps[0][0][0];
  for (int i = tid; i < Kk * Hh; i += 256)
    part[(size_t)blockIdx.x * (Kk * Hh) + i] =
        p0[i] + p0[Kk * Hh + i] + p0[2 * Kk * Hh + i] + p0[3 * Kk * Hh + i];
  if (tid < Kk)
    pcnt[blockIdx.x * Kk + tid] = pc[0][tid] + pc[1][tid] + pc[2][tid] + pc[3][tid];
}

// Reduce 32 block-partials in fixed order; empty clusters keep old center.
__global__ __launch_bounds__(256) void km_update(
    const float* __restrict__ part, const int* __restrict__ pcnt,
    float* __restrict__ cent)
{
  int k = blockIdx.x, c = threadIdx.x;
  int cnt = 0;
  for (int p = 0; p < 32; ++p) cnt += pcnt[p * Kk + k];
  float s = 0.f;
  for (int p = 0; p < 32; ++p) s += part[(size_t)p * (Kk * Hh) + k * Hh + c];
  if (cnt > 0) cent[k * Hh + c] = s / (float)cnt;
}

// ---------------------------------------------------------------------------
// h1 = relu(centers@g1_w + g1_b); h2 = relu(h1@g2_w + g2_b). One block.
__global__ __launch_bounds__(256) void gcn(
    const float* __restrict__ cent, const float* __restrict__ g1w,
    const float* __restrict__ g1b, const float* __restrict__ g2w,
    const float* __restrict__ g2b, float* __restrict__ h2out)
{
  __shared__ float a[Kk][Hh];
  __shared__ float b[Kk][Hh];
  int c = threadIdx.x;
  for (int i = c; i < Kk * Hh; i += 256) ((float*)a)[i] = cent[i];
  __syncthreads();
  float acc[Kk];
  #pragma unroll
  for (int k = 0; k < Kk; ++k) acc[k] = 0.f;
  for (int j = 0; j < Hh; ++j) {
    float wv = g1w[(size_t)j * Hh + c];
    #pragma unroll
    for (int k = 0; k < Kk; ++k) acc[k] += a[k][j] * wv;
  }
  #pragma unroll
  for (int k = 0; k < Kk; ++k) b[k][c] = fmaxf(acc[k] + g1b[c], 0.f);
  __syncthreads();
  #pragma unroll
  for (int k = 0; k < Kk; ++k) acc[k] = 0.f;
  for (int j = 0; j < Hh; ++j) {
    float wv = g2w[(size_t)j * Hh + c];
    #pragma unroll
    for (int k = 0; k < Kk; ++k) acc[k] += b[k][j] * wv;
  }
  #pragma unroll
  for (int k = 0; k < Kk; ++k) h2out[k * Hh + c] = fmaxf(acc[k] + g2b[c], 0.f);
}

// scores = softmax(relu(ht@centers^T)); clu = scores@h2; gated blend. 1 block/row.
__global__ __launch_bounds__(256) void finalk(
    const float* __restrict__ hfin, const float* __restrict__ cent,
    const float* __restrict__ h2, const float* __restrict__ w1w,
    const float* __restrict__ w1b, const float* __restrict__ w2w,
    const float* __restrict__ w2b, float* __restrict__ out)
{
  __shared__ alignas(16) float cs[Kk][Hh];
  __shared__ alignas(16) float hs[Kk][Hh];
  __shared__ float red[4];
  const int tid = threadIdx.x, lane = tid & 63, w = tid >> 6;
  const int n = blockIdx.x;
  for (int i = tid; i < Kk * Hh; i += 256) { ((float*)cs)[i] = cent[i]; ((float*)hs)[i] = h2[i]; }
  float ht = hfin[(size_t)n * Hh + tid];
  __syncthreads();

  auto bred = [&](float v) -> float {
    #pragma unroll
    for (int m = 1; m < 64; m <<= 1) v += __shfl_xor(v, m, 64);
    __syncthreads();
    if (lane == 0) red[w] = v;
    __syncthreads();
    return red[0] + red[1] + red[2] + red[3];
  };

  float ev[Kk];
  #pragma unroll
  for (int k = 0; k < Kk; ++k)
    ev[k] = fmaxf(bred(ht * cs[k][tid]), 0.f);

  float mx = ev[0];
  #pragma unroll
  for (int k = 1; k < Kk; ++k) mx = fmaxf(mx, ev[k]);
  float se = 0.f; float sc[Kk];
  #pragma unroll
  for (int k = 0; k < Kk; ++k) { sc[k] = expf(ev[k] - mx); se += sc[k]; }
  float inv = 1.f / se;
  float clu = 0.f;
  #pragma unroll
  for (int k = 0; k < Kk; ++k) clu += sc[k] * inv * hs[k][tid];

  float r1 = bred(clu * w1w[tid]);
  float r2 = bred(ht * w2w[tid]);
  float a1 = sigm(r1 + w1b[0]);
  float a2 = sigm(r2 + w2b[0]);
  float wn = a1 / (a1 + a2);
  out[(size_t)n * Hh + tid] = wn * clu + (1.f - wn) * ht;
}

// ---------------------------------------------------------------------------
// Host-side threefry2x32 (JAX), reproducing jax.random.permutation(key(42), 2048)[:12].
static void tf2x32(uint32_t k0, uint32_t k1, uint32_t c0, uint32_t c1,
                   uint32_t& o0, uint32_t& o1) {
  uint32_t ks2 = k0 ^ k1 ^ 0x1BD11BDAu;
  uint32_t x0 = c0 + k0, x1 = c1 + k1;
#define TFR(r) do { x0 += x1; x1 = (x1 << (r)) | (x1 >> (32 - (r))); x1 ^= x0; } while (0)
  TFR(13); TFR(15); TFR(26); TFR(6);
  x0 += k1;  x1 += ks2 + 1u;
  TFR(17); TFR(29); TFR(16); TFR(24);
  x0 += ks2; x1 += k0 + 2u;
  TFR(13); TFR(15); TFR(26); TFR(6);
  x0 += k0;  x1 += k1 + 3u;
  TFR(17); TFR(29); TFR(16); TFR(24);
  x0 += k1;  x1 += ks2 + 4u;
  TFR(13); TFR(15); TFR(26); TFR(6);
  x0 += ks2; x1 += k0 + 5u;
#undef TFR
  o0 = x0; o1 = x1;
}

static void compute_idx(int* out12) {
  uint32_t kh = 0u, kl = 42u;     // jax.random.key(42) -> (0, 42)
  std::vector<int> perm(Nn);
  for (int i = 0; i < Nn; ++i) perm[i] = i;
  std::vector<uint32_t> bits(Nn);
  std::vector<int> pos(Nn);
  for (int round = 0; round < 2; ++round) {     // 2 rounds for n=2048
    uint32_t nh, nl, sh, sl;
    tf2x32(kh, kl, 0u, 0u, nh, nl);             // split: counters (0,0),(0,1)
    tf2x32(kh, kl, 0u, 1u, sh, sl);
    kh = nh; kl = nl;
    // partitionable random_bits(32): bits[i] = o0 ^ o1 at counter (0, i)
    for (uint32_t i = 0; i < (uint32_t)Nn; ++i) {
      uint32_t o0, o1; tf2x32(sh, sl, 0u, i, o0, o1); bits[i] = o0 ^ o1;
    }
    for (int i = 0; i < Nn; ++i) pos[i] = i;
    std::stable_sort(pos.begin(), pos.end(),
                     [&](int a, int b) { return bits[a] < bits[b]; });
    std::vector<int> np(Nn);
    for (int i = 0; i < Nn; ++i) np[i] = perm[pos[i]];
    perm.swap(np);
  }
  for (int k = 0; k < Kk; ++k) out12[k] = perm[k];
}

// ---------------------------------------------------------------------------
extern "C" void kernel_launch(void* const* d_in, const int* in_sizes, int n_in,
                              void* d_out, int out_size, void* d_ws, size_t ws_size,
                              hipStream_t stream) {
  const float* x   = (const float*)d_in[0];
  const int*   len = (const int*)d_in[1];
  const float* Wih = (const float*)d_in[2];
  const float* Whh = (const float*)d_in[3];
  const float* bih = (const float*)d_in[4];
  const float* bhh = (const float*)d_in[5];
  const float* w1w = (const float*)d_in[6];
  const float* w1b = (const float*)d_in[7];
  const float* w2w = (const float*)d_in[8];
  const float* w2b = (const float*)d_in[9];
  const float* g1w = (const float*)d_in[10];
  const float* g1b = (const float*)d_in[11];
  const float* g2w = (const float*)d_in[12];
  const float* g2b = (const float*)d_in[13];
  float* out = (float*)d_out;

  float* wsf  = (float*)d_ws;
  float* hfin = wsf;                        // N*H
  float* cent = hfin + (size_t)Nn * Hh;     // K*H
  float* h2g  = cent + Kk * Hh;             // K*H
  float* part = h2g + Kk * Hh;              // 32*K*H
  int*   pcnt = (int*)(part + 32 * Kk * Hh);// 32*K

  IdxArgs ia;
  compute_idx(ia.v);                        // host, deterministic, capture-safe

  gru_rows<<<256, 256, 0, stream>>>(x, len, Wih, Whh, bih, bhh, hfin);

  km_init<<<1, 256, 0, stream>>>(hfin, cent, ia);
  for (int it = 0; it < MAXIT; ++it) {
    km_assign<<<32, 256, 0, stream>>>(hfin, cent, part, pcnt);
    km_update<<<Kk, 256, 0, stream>>>(part, pcnt, cent);
  }

  gcn<<<1, 256, 0, stream>>>(cent, g1w, g1b, g2w, g2b, h2g);
  finalk<<<Nn, 256, 0, stream>>>(hfin, cent, h2g, w1w, w1b, w2w, w2b, out);
}